// Round 1
// 373.529 us; speedup vs baseline: 1.0044x; 1.0044x over previous
//
#include <hip/hip_runtime.h>
#include <math.h>

#define EPS 1e-5f

constexpr int Mc = 8192;   // memory rows per batch
constexpr int Wc = 32;     // word size
constexpr int Hc = 4;      // heads
constexpr int NT = 1024;   // threads per block (16 waves)
constexpr int LD = Mc + 8; // padded LDS row stride: (8h + m) -> conflict-free phase-1 writes

// DPP-based xor-add within 16-lane rows: pure VALU, no LDS pipe, no lgkmcnt waits.
// (HIP __shfl_xor lowers to ds_bpermute_b32 + lgkmcnt -- the hot-loop serializer.)
template <int CTRL>
__device__ __forceinline__ float dpp_xor_add(float x) {
    int moved = __builtin_amdgcn_update_dpp(0, __float_as_int(x), CTRL, 0xF, 0xF, true);
    return x + __int_as_float(moved);
}

// stage controls:
//   0xB1  = quad_perm([1,0,3,2])  -> xor 1
//   0x4E  = quad_perm([2,3,0,1])  -> xor 2
//   0x141 = row_half_mirror (l <-> 7-l in each 8-lane half-row); after stages 1+2
//           every lane of a quad holds the identical quad-sum, so this equals xor 4
//           bitwise -- numerics unchanged vs. the shfl version.
#define XOR_ADD5(C)            \
    sq = dpp_xor_add<C>(sq);   \
    d0 = dpp_xor_add<C>(d0);   \
    d1 = dpp_xor_add<C>(d1);   \
    d2 = dpp_xor_add<C>(d2);   \
    d3 = dpp_xor_add<C>(d3);

__global__ __launch_bounds__(NT, 4) void weightfn_kernel(
    const float* __restrict__ memory,
    const float* __restrict__ keys,
    const float* __restrict__ strengths,
    float* __restrict__ out)
{
    // ~131 KB exp(sharp) buffer; 1 block/CU by design (160 KB LDS on gfx950)
    __shared__ __align__(16) float s_sharp[Hc * LD];   // holds exp(sharp) after phase 1
    __shared__ __align__(16) float s_key[Hc * Wc];
    __shared__ float s_kn[Hc];              // key norms
    __shared__ float s_beta[Hc];            // softplus(strengths)
    __shared__ float s_redl[NT / 64][Hc];   // per-wave partial exp-sums
    __shared__ float s_inv[Hc];             // 1 / softmax denominator

    const int b = blockIdx.x;
    const int t = threadIdx.x;

    // ---- load keys, compute key norms and softplus(strengths) ----
    if (t < Hc * Wc) s_key[t] = keys[(size_t)b * Hc * Wc + t];
    __syncthreads();
    if (t < Hc) {
        float s = 0.f;
        #pragma unroll
        for (int w = 0; w < Wc; ++w) { float k = s_key[t * Wc + w]; s += k * k; }
        s_kn[t] = sqrtf(s + EPS);
        float x = strengths[(size_t)b * Hc + t];
        // numerically stable softplus (fp64-free, matches np within fp32 rounding)
        s_beta[t] = fmaxf(x, 0.f) + log1pf(expf(-fabsf(x)));
    }
    __syncthreads();

    // ---- phase 1: stream memory[b]; exp(sharp) -> LDS; online denominator ----
    // lane layout: 8 lanes per row, lane w4 owns float4 chunk w4 of the row.
    const int w4 = t & 7;
    const int mg = t >> 3;
    const float4* mp = reinterpret_cast<const float4*>(memory) + (size_t)b * (Mc * Wc / 4);
    const float4* kp = reinterpret_cast<const float4*>(s_key);
    const float4 k0 = kp[0 * 8 + w4];
    const float4 k1 = kp[1 * 8 + w4];
    const float4 k2 = kp[2 * 8 + w4];
    const float4 k3 = kp[3 * 8 + w4];
    const float myKn   = s_kn[w4 & 3];
    const float myBeta = s_beta[w4 & 3];

    float esum = 0.f;   // this lane's partial softmax denominator (head = w4, if w4 < 4)

    #pragma unroll 4
    for (int k = 0; k < Mc / (NT / 8); ++k) {   // 64 iterations, 128 rows each
        const int m = mg + k * (NT / 8);
        float4 v = mp[t + k * NT];              // fully coalesced: flat index t + k*1024
        float sq = v.x * v.x + v.y * v.y + v.z * v.z + v.w * v.w;
        float d0 = v.x * k0.x + v.y * k0.y + v.z * k0.z + v.w * k0.w;
        float d1 = v.x * k1.x + v.y * k1.y + v.z * k1.z + v.w * k1.w;
        float d2 = v.x * k2.x + v.y * k2.y + v.z * k2.z + v.w * k2.w;
        float d3 = v.x * k3.x + v.y * k3.y + v.z * k3.z + v.w * k3.w;
        // reduce across the 8 lanes sharing this row: 3-stage DPP butterfly (pure VALU)
        XOR_ADD5(0xB1)    // xor 1
        XOR_ADD5(0x4E)    // xor 2
        XOR_ADD5(0x141)   // cross-quad mirror == xor 4 after stages 1+2
        if (w4 < Hc) {
            float d = (w4 == 0) ? d0 : (w4 == 1) ? d1 : (w4 == 2) ? d2 : d3;
            float mn = sqrtf(sq + EPS);
            // |sharp| <= softplus(max strength) ~ 3.5 -> exp() safe without max-sub
            float e = __expf(d * myBeta * __builtin_amdgcn_rcpf(myKn * mn + EPS));
            s_sharp[w4 * LD + m] = e;
            esum += e;
        }
    }

    // ---- phase 2: block reduction of the per-head denominators ----
    const int wave = t >> 6;
    // xor 8/16/32 preserves lane&7, so head lanes (w4<4) combine with same-head lanes
    // (once per kernel -- bpermute cost irrelevant here)
    #pragma unroll
    for (int off = 8; off <= 32; off <<= 1) esum += __shfl_xor(esum, off);
    if ((t & 63) < Hc) s_redl[wave][w4] = esum;   // lanes 0..3 of each wave
    __syncthreads();
    if (t < Hc) {
        float s = 0.f;
        #pragma unroll
        for (int i = 0; i < NT / 64; ++i) s += s_redl[i][t];
        s_inv[t] = __builtin_amdgcn_rcpf(s);   // s >= 8192*exp(-3.5) > 0, well-scaled
    }
    __syncthreads();

    // ---- phase 3: scale & store, coalesced float4 ----
    float4* op = reinterpret_cast<float4*>(out) + (size_t)b * (Hc * Mc / 4);
    #pragma unroll
    for (int k = 0; k < (Hc * Mc / 4) / NT; ++k) {   // 8 iterations
        const int f = t + k * NT;
        const int h = f >> 11;        // / (Mc/4)
        const int r = f & 2047;       // float4 index within the head row
        float4 v = *reinterpret_cast<const float4*>(&s_sharp[h * LD + r * 4]);
        const float gih = s_inv[h];
        float4 o;
        o.x = v.x * gih;
        o.y = v.y * gih;
        o.z = v.z * gih;
        o.w = v.w * gih;
        op[f] = o;
    }
}

extern "C" void kernel_launch(void* const* d_in, const int* in_sizes, int n_in,
                              void* d_out, int out_size, void* d_ws, size_t ws_size,
                              hipStream_t stream) {
    const float* memory    = (const float*)d_in[0];
    const float* keys      = (const float*)d_in[1];
    const float* strengths = (const float*)d_in[2];
    float* out = (float*)d_out;

    const int B = in_sizes[0] / (Mc * Wc);   // 256
    dim3 grid(B), block(NT);
    hipLaunchKernelGGL(weightfn_kernel, grid, block, 0, stream,
                       memory, keys, strengths, out);
}